// Round 1
// baseline (177.726 us; speedup 1.0000x reference)
//
#include <hip/hip_runtime.h>
#include <hip/hip_bf16.h>

#define NB 64
#define NS 1024
#define DD 256
#define BM 128
#define BK 64

typedef __attribute__((ext_vector_type(4))) float f32x4;
typedef __attribute__((ext_vector_type(8))) short bf16x8;
typedef __attribute__((ext_vector_type(8))) unsigned short u16x8;
typedef __attribute__((ext_vector_type(4))) unsigned short u16x4;

__device__ __forceinline__ unsigned short f2bf(float x) {
  union { float f; unsigned int u; } c; c.f = x;
  unsigned int r = c.u + 0x7fffu + ((c.u >> 16) & 1u);
  return (unsigned short)(r >> 16);
}

// ---- prep: sq[b*NS+row] = sum_k d^2, optionally write bf16 copy ----
__global__ __launch_bounds__(256) void prep_kernel(const float* __restrict__ din,
                                                   unsigned short* __restrict__ dbf,
                                                   float* __restrict__ sq,
                                                   int write_bf) {
  const int row = blockIdx.x * 4 + (threadIdx.x >> 6);
  const int lane = threadIdx.x & 63;
  const float4* src = reinterpret_cast<const float4*>(din + (size_t)row * DD);
  float4 v = src[lane];
  float s = v.x * v.x + v.y * v.y + v.z * v.z + v.w * v.w;
  if (write_bf) {
    u16x4 o;
    o[0] = f2bf(v.x); o[1] = f2bf(v.y); o[2] = f2bf(v.z); o[3] = f2bf(v.w);
    reinterpret_cast<u16x4*>(dbf + (size_t)row * DD)[lane] = o;
  }
  #pragma unroll
  for (int off = 32; off > 0; off >>= 1) s += __shfl_xor(s, off, 64);
  if (lane == 0) sq[row] = s;
}

// ---- denom: sum((W - eye)^2) ----
__global__ __launch_bounds__(256) void denom_kernel(const float* __restrict__ W,
                                                    float* __restrict__ denom2) {
  const int t = blockIdx.x * 256 + threadIdx.x;
  float4 v = reinterpret_cast<const float4*>(W)[t];
  const int e0 = t << 2;
  const int r = e0 >> 10, c0 = e0 & 1023;
  float a0 = v.x - ((c0 + 0) == r ? 1.0f : 0.0f);
  float a1 = v.y - ((c0 + 1) == r ? 1.0f : 0.0f);
  float a2 = v.z - ((c0 + 2) == r ? 1.0f : 0.0f);
  float a3 = v.w - ((c0 + 3) == r ? 1.0f : 0.0f);
  float s = a0 * a0 + a1 * a1 + a2 * a2 + a3 * a3;
  #pragma unroll
  for (int off = 32; off > 0; off >>= 1) s += __shfl_xor(s, off, 64);
  __shared__ float red[4];
  if ((threadIdx.x & 63) == 0) red[threadIdx.x >> 6] = s;
  __syncthreads();
  if (threadIdx.x == 0) atomicAdd(denom2, red[0] + red[1] + red[2] + red[3]);
}

// ---- main: per (tile, batch-group) block: MFMA Gram + fused epilogue ----
// MODE 0: stage bf16 workspace via global_load_lds (16B)
// MODE 1: reg-stage f32 -> bf16 on the fly (no big workspace)
template <int MODE>
__global__ __launch_bounds__(256, 2) void main_kernel(
    const float* __restrict__ dvec, const unsigned short* __restrict__ dbf,
    const float* __restrict__ sq, const float* __restrict__ S,
    const float* __restrict__ W, float* __restrict__ numer2) {
  __shared__ unsigned short As[2][BM * BK];
  __shared__ unsigned short Bs[2][BM * BK];

  const int tid = threadIdx.x;
  const int lane = tid & 63;
  const int wid = tid >> 6;
  const int wr = wid >> 1;
  const int wc = wid & 1;

  const int tile = (int)blockIdx.x >> 3;   // 0..63
  const int g = (int)blockIdx.x & 7;       // batch group
  const int brow = (tile >> 3) * BM;
  const int bcol = (tile & 7) * BM;
  const int b0 = g * 8;

  // staging coords: thread handles 16B at linear LDS offset q*4096 + tid*16
  const int srow = tid >> 3;          // +q*32 -> row 0..127
  const int scol = (tid & 7) * 8;     // k element offset

  f32x4 acc[4][4];
  #pragma unroll
  for (int m = 0; m < 4; ++m)
    #pragma unroll
    for (int n = 0; n < 4; ++n) acc[m][n] = f32x4{0.f, 0.f, 0.f, 0.f};

  auto STAGE = [&](int buf, int it) {
    const int b = b0 + (it >> 2);
    const int kk = (it & 3) * BK;
    if (MODE == 0) {
      const unsigned short* base = dbf + (size_t)b * (NS * DD) + kk + scol;
      #pragma unroll
      for (int q = 0; q < 4; ++q) {
        const int row = q * 32 + srow;
        const unsigned short* ga = base + (size_t)(brow + row) * DD;
        const unsigned short* gb = base + (size_t)(bcol + row) * DD;
        __builtin_amdgcn_global_load_lds(
            (const __attribute__((address_space(1))) void*)ga,
            (__attribute__((address_space(3))) void*)((char*)(&As[buf][0]) + q * 4096 + tid * 16),
            16, 0, 0);
        __builtin_amdgcn_global_load_lds(
            (const __attribute__((address_space(1))) void*)gb,
            (__attribute__((address_space(3))) void*)((char*)(&Bs[buf][0]) + q * 4096 + tid * 16),
            16, 0, 0);
      }
    } else {
      const float* base = dvec + (size_t)b * (NS * DD) + kk + scol;
      #pragma unroll
      for (int q = 0; q < 4; ++q) {
        const int row = q * 32 + srow;
        const float4* ga = reinterpret_cast<const float4*>(base + (size_t)(brow + row) * DD);
        const float4* gb = reinterpret_cast<const float4*>(base + (size_t)(bcol + row) * DD);
        float4 a0 = ga[0], a1 = ga[1];
        float4 c0 = gb[0], c1 = gb[1];
        u16x8 pa, pb;
        pa[0] = f2bf(a0.x); pa[1] = f2bf(a0.y); pa[2] = f2bf(a0.z); pa[3] = f2bf(a0.w);
        pa[4] = f2bf(a1.x); pa[5] = f2bf(a1.y); pa[6] = f2bf(a1.z); pa[7] = f2bf(a1.w);
        pb[0] = f2bf(c0.x); pb[1] = f2bf(c0.y); pb[2] = f2bf(c0.z); pb[3] = f2bf(c0.w);
        pb[4] = f2bf(c1.x); pb[5] = f2bf(c1.y); pb[6] = f2bf(c1.z); pb[7] = f2bf(c1.w);
        *reinterpret_cast<u16x8*>((char*)(&As[buf][0]) + q * 4096 + tid * 16) = pa;
        *reinterpret_cast<u16x8*>((char*)(&Bs[buf][0]) + q * 4096 + tid * 16) = pb;
      }
    }
  };

  STAGE(0, 0);
  __syncthreads();
  int cur = 0;

  // MFMA fragment offsets (elements): row-major [128][BK] LDS tiles.
  // A/B operand: non-K index = lane&15, K walks (lane>>4)*8 + i.
  const int a_off = (wr * 64 + (lane & 15)) * BK + (lane >> 4) * 8;
  const int b_off = (wc * 64 + (lane & 15)) * BK + (lane >> 4) * 8;

  for (int it = 0; it < 32; ++it) {   // 8 batches x 4 K-steps
    if (it + 1 < 32) STAGE(cur ^ 1, it + 1);
    #pragma unroll
    for (int ks = 0; ks < 2; ++ks) {
      bf16x8 af[4], bfv[4];
      #pragma unroll
      for (int m = 0; m < 4; ++m)
        af[m] = *reinterpret_cast<const bf16x8*>(&As[cur][a_off + m * 16 * BK + ks * 32]);
      #pragma unroll
      for (int n = 0; n < 4; ++n)
        bfv[n] = *reinterpret_cast<const bf16x8*>(&Bs[cur][b_off + n * 16 * BK + ks * 32]);
      #pragma unroll
      for (int m = 0; m < 4; ++m)
        #pragma unroll
        for (int n = 0; n < 4; ++n)
          acc[m][n] = __builtin_amdgcn_mfma_f32_16x16x32_bf16(af[m], bfv[n], acc[m][n], 0, 0, 0);
    }
    if ((it & 3) == 3) {
      // epilogue for batch b: C/D layout col=lane&15, row=(lane>>4)*4+reg
      const int b = b0 + (it >> 2);
      const float* sqb = sq + (size_t)b * NS;
      const int hi = lane >> 4, lo = lane & 15;
      float lsum = 0.f;
      float sqc[4];
      #pragma unroll
      for (int n = 0; n < 4; ++n) sqc[n] = sqb[bcol + wc * 64 + n * 16 + lo];
      #pragma unroll
      for (int m = 0; m < 4; ++m) {
        #pragma unroll
        for (int j = 0; j < 4; ++j) {
          const int r = brow + wr * 64 + m * 16 + hi * 4 + j;
          const float sqr = sqb[r];
          const float* Srow = S + (size_t)r * NS;
          const float* Wrow = W + (size_t)r * NS;
          #pragma unroll
          for (int n = 0; n < 4; ++n) {
            const int c = bcol + wc * 64 + n * 16 + lo;
            const float gv = acc[m][n][j];
            float d2 = fmaxf(sqr + sqc[n] - 2.0f * gv, 0.0f);
            const float sv = Srow[c];
            const float wv = Wrow[c];
            const bool diag = (r == c);
            float kd = 0.0f;
            const float d2e = diag ? 1e30f : d2;
            // exp(-sqrt(d2)) is sub-f32-epsilon vs sv once d2>400 (dist>20):
            // skipping it is bit-identical in f32. Wave-uniform branch.
            if (__any(d2e < 400.0f)) {
              kd = __expf(-sqrtf(d2));
              if (diag) kd = 0.0f;
            }
            const float st = diag ? (sv - 1.0f) : sv;
            const float dv = wv * (kd - st);
            lsum = fmaf(dv, dv, lsum);
          }
        }
      }
      #pragma unroll
      for (int off = 32; off > 0; off >>= 1) lsum += __shfl_xor(lsum, off, 64);
      if (lane == 0) atomicAdd(&numer2[b], lsum);
      #pragma unroll
      for (int m = 0; m < 4; ++m)
        #pragma unroll
        for (int n = 0; n < 4; ++n) acc[m][n] = f32x4{0.f, 0.f, 0.f, 0.f};
    }
    __syncthreads();
    cur ^= 1;
  }
}

// ---- final: out = sum_b 2*sqrt(numer2[b]) / sqrt(denom2) ----
__global__ void final_kernel(const float* __restrict__ numer2,
                             const float* __restrict__ denom2,
                             float* __restrict__ out) {
  const int lane = threadIdx.x;
  float v = 2.0f * sqrtf(numer2[lane]);
  #pragma unroll
  for (int off = 32; off > 0; off >>= 1) v += __shfl_xor(v, off, 64);
  if (lane == 0) out[0] = v / sqrtf(denom2[0]);
}

extern "C" void kernel_launch(void* const* d_in, const int* in_sizes, int n_in,
                              void* d_out, int out_size, void* d_ws, size_t ws_size,
                              hipStream_t stream) {
  const float* dvec = (const float*)d_in[0];
  const float* S = (const float*)d_in[1];
  const float* W = (const float*)d_in[2];
  float* out = (float*)d_out;

  const size_t bf_bytes = (size_t)NB * NS * DD * sizeof(unsigned short);  // 32 MiB
  const size_t sq_bytes = (size_t)NB * NS * sizeof(float);                // 256 KiB
  const size_t need_full = bf_bytes + sq_bytes + 65 * sizeof(float);
  const bool full = ws_size >= need_full;

  unsigned short* dbf;
  float* sqp;
  if (full) {
    dbf = (unsigned short*)d_ws;
    sqp = (float*)((char*)d_ws + bf_bytes);
  } else {
    dbf = nullptr;
    sqp = (float*)d_ws;
  }
  float* numer2 = sqp + (size_t)NB * NS;
  float* denom2 = numer2 + NB;

  hipMemsetAsync(numer2, 0, 65 * sizeof(float), stream);
  prep_kernel<<<NB * NS / 4, 256, 0, stream>>>(dvec, dbf, sqp, full ? 1 : 0);
  denom_kernel<<<(NS * NS) / (256 * 4), 256, 0, stream>>>(W, denom2);
  if (full)
    main_kernel<0><<<512, 256, 0, stream>>>(dvec, dbf, sqp, S, W, numer2);
  else
    main_kernel<1><<<512, 256, 0, stream>>>(dvec, dbf, sqp, S, W, numer2);
  final_kernel<<<1, 64, 0, stream>>>(numer2, denom2, out);
}

// Round 2
// 126.660 us; speedup vs baseline: 1.4032x; 1.4032x over previous
//
#include <hip/hip_runtime.h>
#include <hip/hip_bf16.h>

#define NB 64
#define NS 1024
#define DD 256
#define BM 128
#define BK 64
#define NT 36          // upper-triangular 8x8 tile count
#define GB 2           // batches per block
#define THR 120.0f     // dist^2 below which exp(-dist) can matter

typedef __attribute__((ext_vector_type(4))) float f32x4;
typedef __attribute__((ext_vector_type(8))) short bf16x8;
typedef __attribute__((ext_vector_type(8))) unsigned short u16x8;
typedef __attribute__((ext_vector_type(4))) unsigned short u16x4;

__device__ __forceinline__ unsigned short f2bf(float x) {
  union { float f; unsigned int u; } c; c.f = x;
  unsigned int r = c.u + 0x7fffu + ((c.u >> 16) & 1u);
  return (unsigned short)(r >> 16);
}

// ---- prep: sq[b*NS+row] = sum_k d^2, optionally write bf16 copy ----
__global__ __launch_bounds__(256) void prep_kernel(const float* __restrict__ din,
                                                   unsigned short* __restrict__ dbf,
                                                   float* __restrict__ sq,
                                                   int write_bf) {
  const int row = blockIdx.x * 4 + (threadIdx.x >> 6);
  const int lane = threadIdx.x & 63;
  const float4* src = reinterpret_cast<const float4*>(din + (size_t)row * DD);
  float4 v = src[lane];
  float s = v.x * v.x + v.y * v.y + v.z * v.z + v.w * v.w;
  if (write_bf) {
    u16x4 o;
    o[0] = f2bf(v.x); o[1] = f2bf(v.y); o[2] = f2bf(v.z); o[3] = f2bf(v.w);
    reinterpret_cast<u16x4*>(dbf + (size_t)row * DD)[lane] = o;
  }
  #pragma unroll
  for (int off = 32; off > 0; off >>= 1) s += __shfl_xor(s, off, 64);
  if (lane == 0) sq[row] = s;
}

// ---- denom + batch-independent C:  denom2 = sum((W-eye)^2),
//      C = sum_offdiag W*S^2 + sum_diag W*(1-S)^2 ----
__global__ __launch_bounds__(256) void denomC_kernel(const float* __restrict__ S,
                                                     const float* __restrict__ W,
                                                     float* __restrict__ denom2,
                                                     float* __restrict__ Cval) {
  const int t = blockIdx.x * 256 + threadIdx.x;
  float4 w = reinterpret_cast<const float4*>(W)[t];
  float4 s = reinterpret_cast<const float4*>(S)[t];
  const int e0 = t << 2;
  const int r = e0 >> 10, c0 = e0 & 1023;
  float dsum = 0.f, csum = 0.f;
  float wv[4] = {w.x, w.y, w.z, w.w};
  float sv[4] = {s.x, s.y, s.z, s.w};
  #pragma unroll
  for (int i = 0; i < 4; ++i) {
    const bool dg = (c0 + i) == r;
    const float a = wv[i] - (dg ? 1.0f : 0.0f);
    dsum = fmaf(a, a, dsum);
    const float b = dg ? (1.0f - sv[i]) : sv[i];
    csum = fmaf(wv[i] * b, b, csum);   // W binary: W^2 == W
  }
  #pragma unroll
  for (int off = 32; off > 0; off >>= 1) {
    dsum += __shfl_xor(dsum, off, 64);
    csum += __shfl_xor(csum, off, 64);
  }
  __shared__ float redD[4], redC[4];
  if ((threadIdx.x & 63) == 0) { redD[threadIdx.x >> 6] = dsum; redC[threadIdx.x >> 6] = csum; }
  __syncthreads();
  if (threadIdx.x == 0) {
    atomicAdd(denom2, redD[0] + redD[1] + redD[2] + redD[3]);
    atomicAdd(Cval, redC[0] + redC[1] + redC[2] + redC[3]);
  }
}

// ---- main: upper-triangular Gram tiles, MFMA, near-empty epilogue ----
// MODE 0: stage bf16 workspace via global_load_lds (16B)
// MODE 1: reg-stage f32 -> bf16 on the fly (no big workspace)
template <int MODE>
__global__ __launch_bounds__(256, 2) void main_kernel(
    const float* __restrict__ dvec, const unsigned short* __restrict__ dbf,
    const float* __restrict__ sq, const float* __restrict__ S,
    const float* __restrict__ W, float* __restrict__ numer2) {
  __shared__ unsigned short As[2][BM * BK];
  __shared__ unsigned short Bs[2][BM * BK];

  const int tid = threadIdx.x;
  const int lane = tid & 63;
  const int wid = tid >> 6;
  const int wr = wid >> 1;
  const int wc = wid & 1;

  // blockIdx -> (upper tile t, batch group g)
  const int t = (int)blockIdx.x % NT;
  const int g = (int)blockIdx.x / NT;
  int u = t, ti = 0;
  while (u >= 8 - ti) { u -= 8 - ti; ++ti; }
  const int tj = ti + u;
  const int brow = ti * BM;
  const int bcol = tj * BM;
  const bool diag = (ti == tj);
  const int b0 = g * GB;

  const int srow = tid >> 3;          // +q*32 -> row 0..127
  const int scol = (tid & 7) * 8;     // k element offset

  f32x4 acc[4][4];
  #pragma unroll
  for (int m = 0; m < 4; ++m)
    #pragma unroll
    for (int n = 0; n < 4; ++n) acc[m][n] = f32x4{0.f, 0.f, 0.f, 0.f};

  auto STAGE = [&](int buf, int it) {
    const int b = b0 + (it >> 2);
    const int kk = (it & 3) * BK;
    if (MODE == 0) {
      const unsigned short* base = dbf + (size_t)b * (NS * DD) + kk + scol;
      #pragma unroll
      for (int q = 0; q < 4; ++q) {
        const int row = q * 32 + srow;
        const unsigned short* ga = base + (size_t)(brow + row) * DD;
        __builtin_amdgcn_global_load_lds(
            (const __attribute__((address_space(1))) void*)ga,
            (__attribute__((address_space(3))) void*)((char*)(&As[buf][0]) + q * 4096 + tid * 16),
            16, 0, 0);
      }
      if (!diag) {
        #pragma unroll
        for (int q = 0; q < 4; ++q) {
          const int row = q * 32 + srow;
          const unsigned short* gb = base + (size_t)(bcol + row) * DD;
          __builtin_amdgcn_global_load_lds(
              (const __attribute__((address_space(1))) void*)gb,
              (__attribute__((address_space(3))) void*)((char*)(&Bs[buf][0]) + q * 4096 + tid * 16),
              16, 0, 0);
        }
      }
    } else {
      const float* base = dvec + (size_t)b * (NS * DD) + kk + scol;
      #pragma unroll
      for (int q = 0; q < 4; ++q) {
        const int row = q * 32 + srow;
        const float4* ga = reinterpret_cast<const float4*>(base + (size_t)(brow + row) * DD);
        float4 a0 = ga[0], a1 = ga[1];
        u16x8 pa;
        pa[0] = f2bf(a0.x); pa[1] = f2bf(a0.y); pa[2] = f2bf(a0.z); pa[3] = f2bf(a0.w);
        pa[4] = f2bf(a1.x); pa[5] = f2bf(a1.y); pa[6] = f2bf(a1.z); pa[7] = f2bf(a1.w);
        *reinterpret_cast<u16x8*>((char*)(&As[buf][0]) + q * 4096 + tid * 16) = pa;
      }
      if (!diag) {
        #pragma unroll
        for (int q = 0; q < 4; ++q) {
          const int row = q * 32 + srow;
          const float4* gb = reinterpret_cast<const float4*>(base + (size_t)(bcol + row) * DD);
          float4 c0 = gb[0], c1 = gb[1];
          u16x8 pb;
          pb[0] = f2bf(c0.x); pb[1] = f2bf(c0.y); pb[2] = f2bf(c0.z); pb[3] = f2bf(c0.w);
          pb[4] = f2bf(c1.x); pb[5] = f2bf(c1.y); pb[6] = f2bf(c1.z); pb[7] = f2bf(c1.w);
          *reinterpret_cast<u16x8*>((char*)(&Bs[buf][0]) + q * 4096 + tid * 16) = pb;
        }
      }
    }
  };

  STAGE(0, 0);
  __syncthreads();
  int cur = 0;

  const int a_off = (wr * 64 + (lane & 15)) * BK + (lane >> 4) * 8;
  const int b_off = (wc * 64 + (lane & 15)) * BK + (lane >> 4) * 8;
  const int NIT = GB * 4;

  for (int it = 0; it < NIT; ++it) {
    if (it + 1 < NIT) STAGE(cur ^ 1, it + 1);
    const unsigned short* Acur = &As[cur][0];
    const unsigned short* Bcur = diag ? &As[cur][0] : &Bs[cur][0];
    #pragma unroll
    for (int ks = 0; ks < 2; ++ks) {
      bf16x8 af[4], bfv[4];
      #pragma unroll
      for (int m = 0; m < 4; ++m)
        af[m] = *reinterpret_cast<const bf16x8*>(Acur + a_off + m * 16 * BK + ks * 32);
      #pragma unroll
      for (int n = 0; n < 4; ++n)
        bfv[n] = *reinterpret_cast<const bf16x8*>(Bcur + b_off + n * 16 * BK + ks * 32);
      #pragma unroll
      for (int m = 0; m < 4; ++m)
        #pragma unroll
        for (int n = 0; n < 4; ++n)
          acc[m][n] = __builtin_amdgcn_mfma_f32_16x16x32_bf16(af[m], bfv[n], acc[m][n], 0, 0, 0);
    }
    if ((it & 3) == 3) {
      // epilogue for batch b: only the (rare) kd-dependent terms.
      // pair (r,c), r<c: add kd^2*(W[r][c]+W[c][r]) - 2*kd*(W[r][c]S[r][c]+W[c][r]S[c][r])
      const int b = b0 + (it >> 2);
      const float* sqb = sq + (size_t)b * NS;
      const int hi = lane >> 4, lo = lane & 15;
      float lsum = 0.f;
      float sqc[4];
      #pragma unroll
      for (int n = 0; n < 4; ++n) sqc[n] = sqb[bcol + wc * 64 + n * 16 + lo];
      #pragma unroll
      for (int m = 0; m < 4; ++m) {
        #pragma unroll
        for (int j = 0; j < 4; ++j) {
          const int r = brow + wr * 64 + m * 16 + hi * 4 + j;
          const float sqr = sqb[r];
          #pragma unroll
          for (int n = 0; n < 4; ++n) {
            const int c = bcol + wc * 64 + n * 16 + lo;
            const float d2 = fmaxf(sqr + sqc[n] - 2.0f * acc[m][n][j], 0.0f);
            const bool hit = (r < c) && (d2 < THR);
            if (__any(hit)) {
              if (hit) {
                const float kd = __expf(-sqrtf(d2));
                const float wrc = W[(size_t)r * NS + c];
                const float wcr = W[(size_t)c * NS + r];
                const float src_ = S[(size_t)r * NS + c];
                const float scr = S[(size_t)c * NS + r];
                lsum = fmaf(kd, kd * (wrc + wcr) - 2.0f * fmaf(wrc, src_, wcr * scr), lsum);
              }
            }
          }
        }
      }
      if (__any(lsum != 0.f)) {
        #pragma unroll
        for (int off = 32; off > 0; off >>= 1) lsum += __shfl_xor(lsum, off, 64);
        if (lane == 0) atomicAdd(&numer2[b], lsum);
      }
      #pragma unroll
      for (int m = 0; m < 4; ++m)
        #pragma unroll
        for (int n = 0; n < 4; ++n) acc[m][n] = f32x4{0.f, 0.f, 0.f, 0.f};
    }
    __syncthreads();
    cur ^= 1;
  }
}

// ---- final: out = sum_b 2*sqrt(C + numer2[b]) / sqrt(denom2) ----
__global__ void final_kernel(const float* __restrict__ numer2,
                             const float* __restrict__ denom2,
                             const float* __restrict__ Cval,
                             float* __restrict__ out) {
  const int lane = threadIdx.x;
  float v = 2.0f * sqrtf(Cval[0] + numer2[lane]);
  #pragma unroll
  for (int off = 32; off > 0; off >>= 1) v += __shfl_xor(v, off, 64);
  if (lane == 0) out[0] = v / sqrtf(denom2[0]);
}

extern "C" void kernel_launch(void* const* d_in, const int* in_sizes, int n_in,
                              void* d_out, int out_size, void* d_ws, size_t ws_size,
                              hipStream_t stream) {
  const float* dvec = (const float*)d_in[0];
  const float* S = (const float*)d_in[1];
  const float* W = (const float*)d_in[2];
  float* out = (float*)d_out;

  const size_t bf_bytes = (size_t)NB * NS * DD * sizeof(unsigned short);  // 32 MiB
  const size_t sq_bytes = (size_t)NB * NS * sizeof(float);                // 256 KiB
  const size_t need_full = bf_bytes + sq_bytes + 66 * sizeof(float);
  const bool full = ws_size >= need_full;

  unsigned short* dbf;
  float* sqp;
  if (full) {
    dbf = (unsigned short*)d_ws;
    sqp = (float*)((char*)d_ws + bf_bytes);
  } else {
    dbf = nullptr;
    sqp = (float*)d_ws;
  }
  float* numer2 = sqp + (size_t)NB * NS;   // 64 floats
  float* denom2 = numer2 + NB;             // 1
  float* Cval = denom2 + 1;                // 1

  hipMemsetAsync(numer2, 0, 66 * sizeof(float), stream);
  prep_kernel<<<NB * NS / 4, 256, 0, stream>>>(dvec, dbf, sqp, full ? 1 : 0);
  denomC_kernel<<<(NS * NS) / (256 * 4), 256, 0, stream>>>(S, W, denom2, Cval);
  if (full)
    main_kernel<0><<<NT * (NB / GB), 256, 0, stream>>>(dvec, dbf, sqp, S, W, numer2);
  else
    main_kernel<1><<<NT * (NB / GB), 256, 0, stream>>>(dvec, dbf, sqp, S, W, numer2);
  final_kernel<<<1, 64, 0, stream>>>(numer2, denom2, Cval, out);
}

// Round 3
// 108.857 us; speedup vs baseline: 1.6327x; 1.1635x over previous
//
#include <hip/hip_runtime.h>
#include <hip/hip_bf16.h>

#define NB 64
#define NS 1024
#define DD 256
#define BM 128
#define BK 64
#define NT 36          // upper-triangular 8x8 tile count
#define GB 2           // batches per block
#define THR 120.0f     // dist^2 below which exp(-dist) can matter

typedef __attribute__((ext_vector_type(4))) float f32x4;
typedef __attribute__((ext_vector_type(8))) short bf16x8;
typedef __attribute__((ext_vector_type(8))) unsigned short u16x8;
typedef __attribute__((ext_vector_type(4))) unsigned short u16x4;

__device__ __forceinline__ unsigned short f2bf(float x) {
  union { float f; unsigned int u; } c; c.f = x;
  unsigned int r = c.u + 0x7fffu + ((c.u >> 16) & 1u);
  return (unsigned short)(r >> 16);
}

// ---- fused prep (sq + bf16 copy) and denom/C reduction ----
// blocks [0, 16384): prep rows; blocks [16384, 17408): denom + C
__global__ __launch_bounds__(256) void prep_kernel(const float* __restrict__ din,
                                                   unsigned short* __restrict__ dbf,
                                                   float* __restrict__ sq,
                                                   const float* __restrict__ S,
                                                   const float* __restrict__ W,
                                                   float* __restrict__ denom2,
                                                   float* __restrict__ Cval,
                                                   int write_bf) {
  if (blockIdx.x >= 16384) {
    const int t = ((int)blockIdx.x - 16384) * 256 + threadIdx.x;
    float4 w = reinterpret_cast<const float4*>(W)[t];
    float4 s = reinterpret_cast<const float4*>(S)[t];
    const int e0 = t << 2;
    const int r = e0 >> 10, c0 = e0 & 1023;
    float dsum = 0.f, csum = 0.f;
    float wv[4] = {w.x, w.y, w.z, w.w};
    float sv[4] = {s.x, s.y, s.z, s.w};
    #pragma unroll
    for (int i = 0; i < 4; ++i) {
      const bool dg = (c0 + i) == r;
      const float a = wv[i] - (dg ? 1.0f : 0.0f);
      dsum = fmaf(a, a, dsum);
      const float b = dg ? (1.0f - sv[i]) : sv[i];
      csum = fmaf(wv[i] * b, b, csum);   // W binary: W^2 == W
    }
    #pragma unroll
    for (int off = 32; off > 0; off >>= 1) {
      dsum += __shfl_xor(dsum, off, 64);
      csum += __shfl_xor(csum, off, 64);
    }
    __shared__ float redD[4], redC[4];
    if ((threadIdx.x & 63) == 0) { redD[threadIdx.x >> 6] = dsum; redC[threadIdx.x >> 6] = csum; }
    __syncthreads();
    if (threadIdx.x == 0) {
      atomicAdd(denom2, redD[0] + redD[1] + redD[2] + redD[3]);
      atomicAdd(Cval, redC[0] + redC[1] + redC[2] + redC[3]);
    }
    return;
  }
  const int row = blockIdx.x * 4 + (threadIdx.x >> 6);
  const int lane = threadIdx.x & 63;
  const float4* src = reinterpret_cast<const float4*>(din + (size_t)row * DD);
  float4 v = src[lane];
  float s = v.x * v.x + v.y * v.y + v.z * v.z + v.w * v.w;
  if (write_bf) {
    u16x4 o;
    o[0] = f2bf(v.x); o[1] = f2bf(v.y); o[2] = f2bf(v.z); o[3] = f2bf(v.w);
    reinterpret_cast<u16x4*>(dbf + (size_t)row * DD)[lane] = o;
  }
  #pragma unroll
  for (int off = 32; off > 0; off >>= 1) s += __shfl_xor(s, off, 64);
  if (lane == 0) sq[row] = s;
}

// ---- main: upper-triangular Gram tiles, MFMA, near-empty epilogue ----
// LDS tiles are [128][64] bf16 with 16B-chunk XOR swizzle: data chunk c of
// row r lives at LDS chunk (c ^ (r&7)). global_load_lds dest stays LINEAR;
// the inverse permutation is applied to the per-lane GLOBAL source (rule #21).
template <int MODE>
__global__ __launch_bounds__(256, 2) void main_kernel(
    const float* __restrict__ dvec, const unsigned short* __restrict__ dbf,
    const float* __restrict__ sq, const float* __restrict__ S,
    const float* __restrict__ W, float* __restrict__ numer2) {
  __shared__ unsigned short As[2][BM * BK];
  __shared__ unsigned short Bs[2][BM * BK];

  const int tid = threadIdx.x;
  const int lane = tid & 63;
  const int wid = tid >> 6;
  const int wr = wid >> 1;
  const int wc = wid & 1;

  // T1: XCD-chunked bijective swizzle (1152 = 8 * 144). Each XCD gets 144
  // consecutive bids = 4 complete batch-groups (t-fast) -> panel set (~1MB
  // per live group) stays in that XCD's 4MB L2.
  const int orig = (int)blockIdx.x;
  const int bid = (orig & 7) * (NT * (NB / GB) / 8) + (orig >> 3);
  const int t = bid % NT;
  const int g = bid / NT;
  int u = t, ti = 0;
  while (u >= 8 - ti) { u -= 8 - ti; ++ti; }
  const int tj = ti + u;
  const int brow = ti * BM;
  const int bcol = tj * BM;
  const bool diag = (ti == tj);
  const int b0 = g * GB;

  // staging: thread writes LDS linear slot q*4096 + tid*16
  //   -> (row = q*32 + (tid>>3), lds_chunk = tid&7)
  // source global chunk = lds_chunk ^ (row & 7)   (row&7 == (tid>>3)&7, q-indep)
  const int srow = tid >> 3;
  const int scol = (((tid & 7) ^ (srow & 7)) * 8);

  f32x4 acc[4][4];
  #pragma unroll
  for (int m = 0; m < 4; ++m)
    #pragma unroll
    for (int n = 0; n < 4; ++n) acc[m][n] = f32x4{0.f, 0.f, 0.f, 0.f};

  auto STAGE = [&](int buf, int it) {
    const int b = b0 + (it >> 2);
    const int kk = (it & 3) * BK;
    if (MODE == 0) {
      const unsigned short* base = dbf + (size_t)b * (NS * DD) + kk + scol;
      #pragma unroll
      for (int q = 0; q < 4; ++q) {
        const int row = q * 32 + srow;
        const unsigned short* ga = base + (size_t)(brow + row) * DD;
        __builtin_amdgcn_global_load_lds(
            (const __attribute__((address_space(1))) void*)ga,
            (__attribute__((address_space(3))) void*)((char*)(&As[buf][0]) + q * 4096 + tid * 16),
            16, 0, 0);
      }
      if (!diag) {
        #pragma unroll
        for (int q = 0; q < 4; ++q) {
          const int row = q * 32 + srow;
          const unsigned short* gb = base + (size_t)(bcol + row) * DD;
          __builtin_amdgcn_global_load_lds(
              (const __attribute__((address_space(1))) void*)gb,
              (__attribute__((address_space(3))) void*)((char*)(&Bs[buf][0]) + q * 4096 + tid * 16),
              16, 0, 0);
        }
      }
    } else {
      const float* base = dvec + (size_t)b * (NS * DD) + kk + scol;
      #pragma unroll
      for (int q = 0; q < 4; ++q) {
        const int row = q * 32 + srow;
        const float4* ga = reinterpret_cast<const float4*>(base + (size_t)(brow + row) * DD);
        float4 a0 = ga[0], a1 = ga[1];
        u16x8 pa;
        pa[0] = f2bf(a0.x); pa[1] = f2bf(a0.y); pa[2] = f2bf(a0.z); pa[3] = f2bf(a0.w);
        pa[4] = f2bf(a1.x); pa[5] = f2bf(a1.y); pa[6] = f2bf(a1.z); pa[7] = f2bf(a1.w);
        *reinterpret_cast<u16x8*>((char*)(&As[buf][0]) + q * 4096 + tid * 16) = pa;
      }
      if (!diag) {
        #pragma unroll
        for (int q = 0; q < 4; ++q) {
          const int row = q * 32 + srow;
          const float4* gb = reinterpret_cast<const float4*>(base + (size_t)(bcol + row) * DD);
          float4 c0 = gb[0], c1 = gb[1];
          u16x8 pb;
          pb[0] = f2bf(c0.x); pb[1] = f2bf(c0.y); pb[2] = f2bf(c0.z); pb[3] = f2bf(c0.w);
          pb[4] = f2bf(c1.x); pb[5] = f2bf(c1.y); pb[6] = f2bf(c1.z); pb[7] = f2bf(c1.w);
          *reinterpret_cast<u16x8*>((char*)(&Bs[buf][0]) + q * 4096 + tid * 16) = pb;
        }
      }
    }
  };

  STAGE(0, 0);
  __syncthreads();
  int cur = 0;

  // fragment reads: row = (wr*64 + m*16 + (lane&15)), data chunk cd = (lane>>4)+ks*4,
  // LDS chunk = cd ^ (row&7) = cd ^ (lane&7). ks=1 flips chunk bit2 -> offset ^ 32.
  const int xr = lane & 7;
  const int aoffs = (wr * 64 + (lane & 15)) * BK + (((lane >> 4) ^ xr) * 8);
  const int boffs = (wc * 64 + (lane & 15)) * BK + (((lane >> 4) ^ xr) * 8);
  const int NIT = GB * 4;

  for (int it = 0; it < NIT; ++it) {
    if (it + 1 < NIT) STAGE(cur ^ 1, it + 1);
    const unsigned short* Acur = &As[cur][0];
    const unsigned short* Bcur = diag ? &As[cur][0] : &Bs[cur][0];
    #pragma unroll
    for (int ks = 0; ks < 2; ++ks) {
      const int ao = ks ? (aoffs ^ 32) : aoffs;
      const int bo = ks ? (boffs ^ 32) : boffs;
      bf16x8 af[4], bfv[4];
      #pragma unroll
      for (int m = 0; m < 4; ++m)
        af[m] = *reinterpret_cast<const bf16x8*>(Acur + ao + m * 16 * BK);
      #pragma unroll
      for (int n = 0; n < 4; ++n)
        bfv[n] = *reinterpret_cast<const bf16x8*>(Bcur + bo + n * 16 * BK);
      #pragma unroll
      for (int m = 0; m < 4; ++m)
        #pragma unroll
        for (int n = 0; n < 4; ++n)
          acc[m][n] = __builtin_amdgcn_mfma_f32_16x16x32_bf16(af[m], bfv[n], acc[m][n], 0, 0, 0);
    }
    if ((it & 3) == 3) {
      // epilogue for batch b: only the (rare) kd-dependent terms.
      // pair (r,c), r<c: add kd^2*(W[r][c]+W[c][r]) - 2*kd*(W[r][c]S[r][c]+W[c][r]S[c][r])
      const int b = b0 + (it >> 2);
      const float* sqb = sq + (size_t)b * NS;
      const int hi = lane >> 4, lo = lane & 15;
      float lsum = 0.f;
      float sqc[4];
      #pragma unroll
      for (int n = 0; n < 4; ++n) sqc[n] = sqb[bcol + wc * 64 + n * 16 + lo];
      #pragma unroll
      for (int m = 0; m < 4; ++m) {
        #pragma unroll
        for (int j = 0; j < 4; ++j) {
          const int r = brow + wr * 64 + m * 16 + hi * 4 + j;
          const float sqr = sqb[r];
          #pragma unroll
          for (int n = 0; n < 4; ++n) {
            const int c = bcol + wc * 64 + n * 16 + lo;
            const float d2 = fmaxf(sqr + sqc[n] - 2.0f * acc[m][n][j], 0.0f);
            const bool hit = (r < c) && (d2 < THR);
            if (__any(hit)) {
              if (hit) {
                const float kd = __expf(-sqrtf(d2));
                const float wrc = W[(size_t)r * NS + c];
                const float wcr = W[(size_t)c * NS + r];
                const float src_ = S[(size_t)r * NS + c];
                const float scr = S[(size_t)c * NS + r];
                lsum = fmaf(kd, kd * (wrc + wcr) - 2.0f * fmaf(wrc, src_, wcr * scr), lsum);
              }
            }
          }
        }
      }
      if (__any(lsum != 0.f)) {
        #pragma unroll
        for (int off = 32; off > 0; off >>= 1) lsum += __shfl_xor(lsum, off, 64);
        if (lane == 0) atomicAdd(&numer2[b], lsum);
      }
      #pragma unroll
      for (int m = 0; m < 4; ++m)
        #pragma unroll
        for (int n = 0; n < 4; ++n) acc[m][n] = f32x4{0.f, 0.f, 0.f, 0.f};
    }
    __syncthreads();
    cur ^= 1;
  }
}

// ---- final: out = sum_b 2*sqrt(C + numer2[b]) / sqrt(denom2) ----
__global__ void final_kernel(const float* __restrict__ numer2,
                             const float* __restrict__ denom2,
                             const float* __restrict__ Cval,
                             float* __restrict__ out) {
  const int lane = threadIdx.x;
  float v = 2.0f * sqrtf(Cval[0] + numer2[lane]);
  #pragma unroll
  for (int off = 32; off > 0; off >>= 1) v += __shfl_xor(v, off, 64);
  if (lane == 0) out[0] = v / sqrtf(denom2[0]);
}

extern "C" void kernel_launch(void* const* d_in, const int* in_sizes, int n_in,
                              void* d_out, int out_size, void* d_ws, size_t ws_size,
                              hipStream_t stream) {
  const float* dvec = (const float*)d_in[0];
  const float* S = (const float*)d_in[1];
  const float* W = (const float*)d_in[2];
  float* out = (float*)d_out;

  const size_t bf_bytes = (size_t)NB * NS * DD * sizeof(unsigned short);  // 32 MiB
  const size_t sq_bytes = (size_t)NB * NS * sizeof(float);                // 256 KiB
  const size_t need_full = bf_bytes + sq_bytes + 66 * sizeof(float);
  const bool full = ws_size >= need_full;

  unsigned short* dbf;
  float* sqp;
  if (full) {
    dbf = (unsigned short*)d_ws;
    sqp = (float*)((char*)d_ws + bf_bytes);
  } else {
    dbf = nullptr;
    sqp = (float*)d_ws;
  }
  float* numer2 = sqp + (size_t)NB * NS;   // 64 floats
  float* denom2 = numer2 + NB;             // 1
  float* Cval = denom2 + 1;                // 1

  hipMemsetAsync(numer2, 0, 66 * sizeof(float), stream);
  prep_kernel<<<16384 + 1024, 256, 0, stream>>>(dvec, dbf, sqp, S, W, denom2, Cval,
                                                full ? 1 : 0);
  if (full)
    main_kernel<0><<<NT * (NB / GB), 256, 0, stream>>>(dvec, dbf, sqp, S, W, numer2);
  else
    main_kernel<1><<<NT * (NB / GB), 256, 0, stream>>>(dvec, dbf, sqp, S, W, numer2);
  final_kernel<<<1, 64, 0, stream>>>(numer2, denom2, Cval, out);
}